// Round 1
// baseline (2226.038 us; speedup 1.0000x reference)
//
#include <hip/hip_runtime.h>
#include <cstddef>
#include <cstdint>

#define HW 65536

typedef float f32x4 __attribute__((ext_vector_type(4)));

// ---------------------------------------------------------------------------
// Kernel A: per-pixel channel LayerNorm (32ch) + 1x1 convs (32->128 q, 32->256 kv)
// One thread per pixel. Weights staged in LDS, read as wave-uniform float4
// broadcasts (4 FMA per LDS instr).
// ---------------------------------------------------------------------------
__global__ __launch_bounds__(256) void k_ln_conv1(
    const float* __restrict__ lms, const float* __restrict__ pan,
    const float* __restrict__ g_ms, const float* __restrict__ g_pan,
    const float* __restrict__ qw1, const float* __restrict__ qb1,
    const float* __restrict__ kvw1, const float* __restrict__ kvb1,
    float* __restrict__ q_pre, float* __restrict__ kv_pre)
{
    __shared__ float wq[128 * 32];
    __shared__ float wkv[256 * 32];
    const int t = threadIdx.x;
    for (int i = t; i < 128 * 32; i += 256) wq[i] = qw1[i];
    for (int i = t; i < 256 * 32; i += 256) wkv[i] = kvw1[i];
    __syncthreads();

    const int p = blockIdx.x * 256 + t;
    float x[32];

    // ---- pan -> LN -> q 1x1 ----
    {
        float s = 0.f, ss = 0.f;
        #pragma unroll
        for (int c = 0; c < 32; c++) {
            float v = pan[c * HW + p];
            x[c] = v; s += v; ss += v * v;
        }
        float mean = s * (1.f / 32.f);
        float var  = ss * (1.f / 32.f) - mean * mean;
        float rs = rsqrtf(var + 1e-5f);
        #pragma unroll
        for (int c = 0; c < 32; c++) x[c] = (x[c] - mean) * rs * g_pan[c];

        for (int o = 0; o < 128; o++) {
            const float4* w4 = (const float4*)(wq + o * 32);
            float a = qb1[o];
            #pragma unroll
            for (int i4 = 0; i4 < 8; i4++) {
                float4 w = w4[i4];
                a += x[i4*4+0]*w.x + x[i4*4+1]*w.y + x[i4*4+2]*w.z + x[i4*4+3]*w.w;
            }
            q_pre[o * HW + p] = a;
        }
    }
    // ---- lms -> LN -> kv 1x1 ----
    {
        float s = 0.f, ss = 0.f;
        #pragma unroll
        for (int c = 0; c < 32; c++) {
            float v = lms[c * HW + p];
            x[c] = v; s += v; ss += v * v;
        }
        float mean = s * (1.f / 32.f);
        float var  = ss * (1.f / 32.f) - mean * mean;
        float rs = rsqrtf(var + 1e-5f);
        #pragma unroll
        for (int c = 0; c < 32; c++) x[c] = (x[c] - mean) * rs * g_ms[c];

        for (int o = 0; o < 256; o++) {
            const float4* w4 = (const float4*)(wkv + o * 32);
            float a = kvb1[o];
            #pragma unroll
            for (int i4 = 0; i4 < 8; i4++) {
                float4 w = w4[i4];
                a += x[i4*4+0]*w.x + x[i4*4+1]*w.y + x[i4*4+2]*w.z + x[i4*4+3]*w.w;
            }
            kv_pre[o * HW + p] = a;
        }
    }
}

// ---------------------------------------------------------------------------
// Kernel B: depthwise 3x3 conv (SAME, zero pad) + bias.
// Block = (channel, strip of 8 rows). Rows staged in LDS with zero-padded ends.
// Output written directly in WINDOWED layout [c][wi][m] so the attention
// kernel reads coalesced:  wi=(hp%16)*16+(wp%16), m=(hp/16)*16+(wp/16).
// ---------------------------------------------------------------------------
__global__ __launch_bounds__(256) void k_dw3x3(
    const float* __restrict__ src, const float* __restrict__ w9,
    const float* __restrict__ bias, float* __restrict__ dst)
{
    const int t  = threadIdx.x;
    const int c  = blockIdx.x >> 5;
    const int rb = blockIdx.x & 31;
    const int r0 = rb * 8;
    __shared__ float rows[10][258];
    for (int r = 0; r < 10; r++) {
        int hp = r0 + r - 1;
        rows[r][t + 1] = (hp >= 0 && hp < 256) ? src[c * HW + hp * 256 + t] : 0.f;
    }
    if (t < 10) { rows[t][0] = 0.f; rows[t][257] = 0.f; }
    __syncthreads();

    float w[9];
    #pragma unroll
    for (int k = 0; k < 9; k++) w[k] = w9[c * 9 + k];
    const float b = bias[c];
    const int jc = t & 15;   // wp % 16 -> window col
    const int j1 = t >> 4;   // wp / 16 -> m col

    for (int r = 0; r < 8; r++) {
        const int hp = r0 + r;
        float acc = b;
        #pragma unroll
        for (int dy = 0; dy < 3; dy++) {
            const float* rr = rows[r + dy];
            acc += rr[t] * w[dy*3] + rr[t+1] * w[dy*3+1] + rr[t+2] * w[dy*3+2];
        }
        const int wi = (hp & 15) * 16 + jc;
        const int m  = (hp >> 4) * 16 + j1;
        dst[(c * 256 + wi) * 256 + m] = acc;
    }
}

// ---------------------------------------------------------------------------
// Kernel C: attention, one (window, head) per 128-thread block.
// ROW-PER-LANE mapping: wave w lane l owns rows r0=w*128+l and r1=r0+64
// completely (all 256 n). Consequences:
//   - online softmax (M,L) is lane-local: no cross-wave merge, no Mw/Lw LDS.
//   - PV output needs no cross-wave reduce: direct coalesced stores.
//   - attn written 64B-contiguous PER LANE: 16 columns buffered in registers,
//     flushed as 4 back-to-back dwordx4 nontemporal stores -> full 64B lines,
//     killing the 2.9x partial-line write amplification of the old mapping.
// Cost: each K/V LDS broadcast feeds 2 rows instead of 4 (2x ds_read count),
// hidden under the FMA floor.
// ---------------------------------------------------------------------------
__global__ __launch_bounds__(128) void k_attn(
    const float* __restrict__ q_win, const float* __restrict__ kv_win,
    float* __restrict__ attn, float* __restrict__ out_ws)
{
    const int bid = blockIdx.x;
    const int wi = bid >> 3;
    const int h  = bid & 7;
    __shared__ float Ks[16 * 256];
    __shared__ float Vs[16 * 256];
    __shared__ float partial[128];
    __shared__ float rnorm_s[16];
    const int t = threadIdx.x;
    const int wave = t >> 6;
    const int lane = t & 63;

    // ---- load K/V tiles (coalesced float4) ----
    for (int i = t; i < 1024; i += 128) {
        int d = i >> 6, m4 = i & 63;
        int ck = h * 16 + d;
        ((float4*)Ks)[(d << 6) + m4] =
            ((const float4*)kv_win)[((size_t)(ck * 256 + wi) << 6) + m4];
        ((float4*)Vs)[(d << 6) + m4] =
            ((const float4*)kv_win)[((size_t)((ck + 128) * 256 + wi) << 6) + m4];
    }
    __syncthreads();

    // ---- k row norms (over m, per d): 8 partials per d ----
    {
        int d = t >> 3, part = t & 7;
        float ssum = 0.f;
        #pragma unroll
        for (int j = 0; j < 32; j++) {
            float v = Ks[d * 256 + part * 32 + j];
            ssum += v * v;
        }
        partial[t] = ssum;
    }
    __syncthreads();
    if (t < 16) {
        float ssum = 0.f;
        #pragma unroll
        for (int j = 0; j < 8; j++) ssum += partial[t * 8 + j];
        rnorm_s[t] = 1.f / fmaxf(sqrtf(ssum), 1e-12f);
    }
    __syncthreads();

    // ---- rows owned by this thread ----
    const int r0 = (wave << 7) + lane;
    const int r1 = r0 + 64;

    // ---- Q -> registers, scaled by rnorm[d] (coalesced 4B loads) ----
    float q0[16], q1[16];
    #pragma unroll
    for (int d = 0; d < 16; d++) {
        const float* qb = q_win + ((size_t)((h * 16 + d) * 256 + wi) << 8);
        float rn = rnorm_s[d];
        q0[d] = qb[r0] * rn;
        q1[d] = qb[r1] * rn;
    }

    // ---- pass 1: lane-local online max / sumexp over the full row ----
    float M0 = -1e30f, M1 = -1e30f, L0 = 0.f, L1 = 0.f;
    for (int n0 = 0; n0 < 256; n0 += 4) {
        float s0[4] = {}, s1[4] = {};
        #pragma unroll
        for (int d = 0; d < 16; d++) {
            float4 kk = *(const float4*)(Ks + d * 256 + n0);  // broadcast
            float a = q0[d], b = q1[d];
            s0[0] += a * kk.x; s0[1] += a * kk.y; s0[2] += a * kk.z; s0[3] += a * kk.w;
            s1[0] += b * kk.x; s1[1] += b * kk.y; s1[2] += b * kk.z; s1[3] += b * kk.w;
        }
        {
            float mx = fmaxf(fmaxf(s0[0], s0[1]), fmaxf(s0[2], s0[3]));
            float Mn = fmaxf(M0, mx);
            L0 = L0 * __expf(M0 - Mn)
               + __expf(s0[0] - Mn) + __expf(s0[1] - Mn)
               + __expf(s0[2] - Mn) + __expf(s0[3] - Mn);
            M0 = Mn;
        }
        {
            float mx = fmaxf(fmaxf(s1[0], s1[1]), fmaxf(s1[2], s1[3]));
            float Mn = fmaxf(M1, mx);
            L1 = L1 * __expf(M1 - Mn)
               + __expf(s1[0] - Mn) + __expf(s1[1] - Mn)
               + __expf(s1[2] - Mn) + __expf(s1[3] - Mn);
            M1 = Mn;
        }
    }
    const float R0 = 1.f / L0, R1 = 1.f / L1;

    // ---- pass 2: recompute, write attn (full-line nt stores), accumulate PV ----
    float op0[16] = {}, op1[16] = {};
    float* arow0 = attn + ((size_t)(wi * 8 + h) << 16) + ((size_t)r0 << 8);
    float* arow1 = attn + ((size_t)(wi * 8 + h) << 16) + ((size_t)r1 << 8);

    for (int cg = 0; cg < 16; cg++) {           // 16-column groups (64B rows)
        float p0[16], p1[16];
        #pragma unroll
        for (int c4 = 0; c4 < 4; c4++) {
            const int n0 = (cg << 4) + (c4 << 2);
            float s0[4] = {}, s1[4] = {};
            #pragma unroll
            for (int d = 0; d < 16; d++) {
                float4 kk = *(const float4*)(Ks + d * 256 + n0);
                float a = q0[d], b = q1[d];
                s0[0] += a * kk.x; s0[1] += a * kk.y; s0[2] += a * kk.z; s0[3] += a * kk.w;
                s1[0] += b * kk.x; s1[1] += b * kk.y; s1[2] += b * kk.z; s1[3] += b * kk.w;
            }
            #pragma unroll
            for (int j = 0; j < 4; j++) {
                p0[(c4 << 2) + j] = __expf(s0[j] - M0) * R0;
                p1[(c4 << 2) + j] = __expf(s1[j] - M1) * R1;
            }
            #pragma unroll
            for (int d = 0; d < 16; d++) {
                float4 vv = *(const float4*)(Vs + d * 256 + n0);  // broadcast
                op0[d] += p0[(c4<<2)+0] * vv.x + p0[(c4<<2)+1] * vv.y
                        + p0[(c4<<2)+2] * vv.z + p0[(c4<<2)+3] * vv.w;
                op1[d] += p1[(c4<<2)+0] * vv.x + p1[(c4<<2)+1] * vv.y
                        + p1[(c4<<2)+2] * vv.z + p1[(c4<<2)+3] * vv.w;
            }
        }
        // flush: per lane, 4 consecutive dwordx4 -> one complete 64B line per row
        #pragma unroll
        for (int j4 = 0; j4 < 4; j4++) {
            f32x4 v0 = { p0[(j4<<2)+0], p0[(j4<<2)+1], p0[(j4<<2)+2], p0[(j4<<2)+3] };
            __builtin_nontemporal_store(v0, (f32x4*)(arow0 + (cg << 4) + (j4 << 2)));
        }
        #pragma unroll
        for (int j4 = 0; j4 < 4; j4++) {
            f32x4 v1 = { p1[(j4<<2)+0], p1[(j4<<2)+1], p1[(j4<<2)+2], p1[(j4<<2)+3] };
            __builtin_nontemporal_store(v1, (f32x4*)(arow1 + (cg << 4) + (j4 << 2)));
        }
    }

    // ---- PV output: lane-local rows -> direct coalesced stores ----
    #pragma unroll
    for (int d = 0; d < 16; d++) {
        float* ob = out_ws + ((size_t)((h * 16 + d) * 256 + wi) << 8);
        ob[r0] = op0[d];
        ob[r1] = op1[d];
    }
}

// ---------------------------------------------------------------------------
// Kernel D: un-window out_ws [c][wi][m] -> NCHW image via LDS transpose.
// ---------------------------------------------------------------------------
__global__ __launch_bounds__(256) void k_unwin(
    const float* __restrict__ src, float* __restrict__ dst)
{
    const int c  = blockIdx.x >> 4;
    const int i2 = blockIdx.x & 15;
    __shared__ float lds[16 * 257];
    const int t = threadIdx.x;
    #pragma unroll
    for (int j2 = 0; j2 < 16; j2++)
        lds[j2 * 257 + t] = src[((size_t)(c * 256 + i2 * 16 + j2) << 8) + t];
    __syncthreads();
    #pragma unroll
    for (int i1 = 0; i1 < 16; i1++) {
        dst[(size_t)c * HW + (i1 * 16 + i2) * 256 + t] =
            lds[(t & 15) * 257 + i1 * 16 + (t >> 4)];
    }
}

// ---------------------------------------------------------------------------
extern "C" void kernel_launch(void* const* d_in, const int* in_sizes, int n_in,
                              void* d_out, int out_size, void* d_ws, size_t ws_size,
                              hipStream_t stream)
{
    const float* lms   = (const float*)d_in[0];
    const float* pan   = (const float*)d_in[1];
    const float* g_ms  = (const float*)d_in[2];
    const float* g_pan = (const float*)d_in[3];
    const float* qw1   = (const float*)d_in[4];
    const float* qb1   = (const float*)d_in[5];
    const float* qw2   = (const float*)d_in[6];
    const float* qb2   = (const float*)d_in[7];
    const float* kvw1  = (const float*)d_in[8];
    const float* kvb1  = (const float*)d_in[9];
    const float* kvw2  = (const float*)d_in[10];
    const float* kvb2  = (const float*)d_in[11];

    float* attn   = (float*)d_out;                       // 256*8*256*256 fp32
    float* outimg = attn + (size_t)134217728;            // 128*256*256 fp32

    char* ws = (char*)d_ws;
    float* q_win  = (float*)(ws);                        //  32 MB [c][wi][m]
    float* kv_win = (float*)(ws + (size_t)33554432);     //  64 MB [c][wi][m]
    float* q_pre  = (float*)(ws + (size_t)100663296);    //  32 MB NCHW
    float* kv_pre = (float*)(ws + (size_t)134217728);    //  64 MB NCHW
    float* out_ws = q_pre;  // overlay: q_pre dead once k_dw3x3(q) is done

    hipLaunchKernelGGL(k_ln_conv1, dim3(256), dim3(256), 0, stream,
                       lms, pan, g_ms, g_pan, qw1, qb1, kvw1, kvb1, q_pre, kv_pre);
    hipLaunchKernelGGL(k_dw3x3, dim3(128 * 32), dim3(256), 0, stream,
                       q_pre, qw2, qb2, q_win);
    hipLaunchKernelGGL(k_dw3x3, dim3(256 * 32), dim3(256), 0, stream,
                       kv_pre, kvw2, kvb2, kv_win);
    hipLaunchKernelGGL(k_attn, dim3(2048), dim3(128), 0, stream,
                       q_win, kv_win, attn, out_ws);
    hipLaunchKernelGGL(k_unwin, dim3(2048), dim3(256), 0, stream,
                       out_ws, outimg);
}

// Round 2
// 882.345 us; speedup vs baseline: 2.5229x; 2.5229x over previous
//
#include <hip/hip_runtime.h>
#include <cstddef>
#include <cstdint>

#define HW 65536

typedef float f32x4 __attribute__((ext_vector_type(4)));

// ---------------------------------------------------------------------------
// Kernel A: per-pixel channel LayerNorm (32ch) + 1x1 convs (32->128 q, 32->256 kv)
// ---------------------------------------------------------------------------
__global__ __launch_bounds__(256) void k_ln_conv1(
    const float* __restrict__ lms, const float* __restrict__ pan,
    const float* __restrict__ g_ms, const float* __restrict__ g_pan,
    const float* __restrict__ qw1, const float* __restrict__ qb1,
    const float* __restrict__ kvw1, const float* __restrict__ kvb1,
    float* __restrict__ q_pre, float* __restrict__ kv_pre)
{
    __shared__ float wq[128 * 32];
    __shared__ float wkv[256 * 32];
    const int t = threadIdx.x;
    for (int i = t; i < 128 * 32; i += 256) wq[i] = qw1[i];
    for (int i = t; i < 256 * 32; i += 256) wkv[i] = kvw1[i];
    __syncthreads();

    const int p = blockIdx.x * 256 + t;
    float x[32];

    {
        float s = 0.f, ss = 0.f;
        #pragma unroll
        for (int c = 0; c < 32; c++) {
            float v = pan[c * HW + p];
            x[c] = v; s += v; ss += v * v;
        }
        float mean = s * (1.f / 32.f);
        float var  = ss * (1.f / 32.f) - mean * mean;
        float rs = rsqrtf(var + 1e-5f);
        #pragma unroll
        for (int c = 0; c < 32; c++) x[c] = (x[c] - mean) * rs * g_pan[c];

        for (int o = 0; o < 128; o++) {
            const float4* w4 = (const float4*)(wq + o * 32);
            float a = qb1[o];
            #pragma unroll
            for (int i4 = 0; i4 < 8; i4++) {
                float4 w = w4[i4];
                a += x[i4*4+0]*w.x + x[i4*4+1]*w.y + x[i4*4+2]*w.z + x[i4*4+3]*w.w;
            }
            q_pre[o * HW + p] = a;
        }
    }
    {
        float s = 0.f, ss = 0.f;
        #pragma unroll
        for (int c = 0; c < 32; c++) {
            float v = lms[c * HW + p];
            x[c] = v; s += v; ss += v * v;
        }
        float mean = s * (1.f / 32.f);
        float var  = ss * (1.f / 32.f) - mean * mean;
        float rs = rsqrtf(var + 1e-5f);
        #pragma unroll
        for (int c = 0; c < 32; c++) x[c] = (x[c] - mean) * rs * g_ms[c];

        for (int o = 0; o < 256; o++) {
            const float4* w4 = (const float4*)(wkv + o * 32);
            float a = kvb1[o];
            #pragma unroll
            for (int i4 = 0; i4 < 8; i4++) {
                float4 w = w4[i4];
                a += x[i4*4+0]*w.x + x[i4*4+1]*w.y + x[i4*4+2]*w.z + x[i4*4+3]*w.w;
            }
            kv_pre[o * HW + p] = a;
        }
    }
}

// ---------------------------------------------------------------------------
// Kernel B: depthwise 3x3 conv (SAME, zero pad) + bias, windowed output.
// Block = (channel, 16-row strip). A 16-row strip covers ALL 256 wi values
// and exactly 16 consecutive m values (m = rb*16 + j1). Output staged in LDS
// then flushed as wave stores of 64B row segments (16 rows x 64B per instr)
// instead of the old 4B-at-1KB-stride scatter.
// ---------------------------------------------------------------------------
__global__ __launch_bounds__(256) void k_dw3x3(
    const float* __restrict__ src, const float* __restrict__ w9,
    const float* __restrict__ bias, float* __restrict__ dst)
{
    const int t  = threadIdx.x;
    const int c  = blockIdx.x >> 4;
    const int rb = blockIdx.x & 15;
    const int r0 = rb * 16;
    __shared__ float rows[18][258];
    __shared__ float sOut[256 * 20];   // [wi_local][m_local], pad 20 for banks

    for (int i = t; i < 18 * 256; i += 256) {
        int r = i >> 8, col = i & 255;
        int hp = r0 + r - 1;
        rows[r][col + 1] = (hp >= 0 && hp < 256) ? src[c * HW + hp * 256 + col] : 0.f;
    }
    if (t < 18) { rows[t][0] = 0.f; rows[t][257] = 0.f; }
    __syncthreads();

    float w[9];
    #pragma unroll
    for (int k = 0; k < 9; k++) w[k] = w9[c * 9 + k];
    const float b = bias[c];
    const int jc = t & 15;   // wp % 16 -> window col
    const int j1 = t >> 4;   // wp / 16 -> m col (0..15)

    for (int r = 0; r < 16; r++) {
        float acc = b;
        #pragma unroll
        for (int dy = 0; dy < 3; dy++) {
            const float* rr = rows[r + dy];
            acc += rr[t] * w[dy*3] + rr[t+1] * w[dy*3+1] + rr[t+2] * w[dy*3+2];
        }
        // hp = r0 + r, hp&15 == r, hp>>4 == rb
        sOut[(r * 16 + jc) * 20 + j1] = acc;
    }
    __syncthreads();

    for (int i = t; i < 1024; i += 256) {
        int wiL = i >> 2, qj = i & 3;
        const float* sp = sOut + wiL * 20 + qj * 4;
        float4 v = make_float4(sp[0], sp[1], sp[2], sp[3]);
        *(float4*)(dst + (size_t)(c * 256 + wiL) * 256 + r0 + qj * 4) = v;
    }
}

// ---------------------------------------------------------------------------
// Kernel C: attention, one (window, head) per 256-thread block (4 waves).
// COLUMN-PER-LANE, single pass:
//   - lane l holds K cols 4l..4l+3 in 64 VGPRs (rnorm folded in).
//   - Q staged transposed in LDS (Qt[m][16]); wave w owns rows 64w..64w+63.
//   - per row: 64 FMA -> full 256-col score across wave; exact softmax via
//     two 6-step shfl_xor butterflies; attn store = ONE wave instruction
//     covering the full contiguous 1KB row (full 128B lines, no write amp).
//   - PV per 4-row chunk via wave-private LDS P-stage (overlays dead K tile);
//     lane = (d=l>>2, r=l&3), strides padded to 260 for bank spread.
// ---------------------------------------------------------------------------
__global__ __launch_bounds__(256) void k_attn(
    const float* __restrict__ q_win, const float* __restrict__ kv_win,
    float* __restrict__ attn, float* __restrict__ out_ws)
{
    const int bid = blockIdx.x;
    const int wi = bid >> 3;
    const int h  = bid & 7;
    __shared__ float KsP[16 * 256 + 64];   // K tile during setup; P-stage after
    __shared__ float Vs[16 * 260];         // padded stride 260
    __shared__ float Qt[256 * 16];         // [m][d]
    __shared__ float partial[256];
    __shared__ float rnorm_s[16];
    const int t = threadIdx.x;
    const int w = t >> 6;
    const int l = t & 63;

    // ---- load K (linear) and V (padded) tiles, coalesced float4 ----
    for (int i = t; i < 1024; i += 256) {
        int d = i >> 6, m4 = i & 63;
        int ck = h * 16 + d;
        float4 kk = ((const float4*)kv_win)[((size_t)(ck * 256 + wi) << 6) + m4];
        *(float4*)(KsP + d * 256 + 4 * m4) = kk;
        float4 vv = ((const float4*)kv_win)[((size_t)((ck + 128) * 256 + wi) << 6) + m4];
        *(float4*)(Vs + d * 260 + 4 * m4) = vv;
    }
    // ---- load Qt[m][d]: wave w covers d-group 4w..4w+3 for all m ----
    {
        const int d0 = w * 4;
        for (int mi = 0; mi < 4; mi++) {
            int m = l + 64 * mi;
            float4 qv;
            qv.x = q_win[((size_t)((h*16 + d0+0) * 256 + wi) << 8) + m];
            qv.y = q_win[((size_t)((h*16 + d0+1) * 256 + wi) << 8) + m];
            qv.z = q_win[((size_t)((h*16 + d0+2) * 256 + wi) << 8) + m];
            qv.w = q_win[((size_t)((h*16 + d0+3) * 256 + wi) << 8) + m];
            *(float4*)(Qt + m * 16 + d0) = qv;
        }
    }
    __syncthreads();

    // ---- k row norms (per d, over 256 positions) ----
    {
        int d = t >> 4, part = t & 15;
        float ssum = 0.f;
        #pragma unroll
        for (int j = 0; j < 16; j++) {
            float v = KsP[d * 256 + part * 16 + j];
            ssum += v * v;
        }
        partial[t] = ssum;
    }
    __syncthreads();
    if (t < 16) {
        float ssum = 0.f;
        #pragma unroll
        for (int j = 0; j < 16; j++) ssum += partial[t * 16 + j];
        rnorm_s[t] = 1.f / fmaxf(sqrtf(ssum), 1e-12f);
    }
    __syncthreads();

    // ---- K fragment -> registers, rnorm folded in ----
    float4 Kreg[16];
    #pragma unroll
    for (int d = 0; d < 16; d++) {
        float4 kk = *(const float4*)(KsP + d * 256 + 4 * l);
        float rn = rnorm_s[d];
        kk.x *= rn; kk.y *= rn; kk.z *= rn; kk.w *= rn;
        Kreg[d] = kk;
    }
    __syncthreads();   // K tile fully consumed; KsP becomes P-stage

    float* Pst = KsP + w * (4 * 260);      // wave-private 4x260
    float* arow = attn + ((size_t)(wi * 8 + h) << 16);
    const int mbase = w * 64;

    for (int c4 = 0; c4 < 16; c4++) {
        // ---- Phase A: 4 rows, full softmax, full-row attn stores ----
        #pragma unroll
        for (int r = 0; r < 4; r++) {
            const int m = mbase + c4 * 4 + r;
            const float4 qa = *(const float4*)(Qt + m * 16 + 0);
            const float4 qb = *(const float4*)(Qt + m * 16 + 4);
            const float4 qc = *(const float4*)(Qt + m * 16 + 8);
            const float4 qd = *(const float4*)(Qt + m * 16 + 12);
            float qs[16] = { qa.x,qa.y,qa.z,qa.w, qb.x,qb.y,qb.z,qb.w,
                             qc.x,qc.y,qc.z,qc.w, qd.x,qd.y,qd.z,qd.w };
            float4 s = make_float4(0.f, 0.f, 0.f, 0.f);
            #pragma unroll
            for (int d = 0; d < 16; d++) {
                float q = qs[d];
                s.x += q * Kreg[d].x; s.y += q * Kreg[d].y;
                s.z += q * Kreg[d].z; s.w += q * Kreg[d].w;
            }
            float mx = fmaxf(fmaxf(s.x, s.y), fmaxf(s.z, s.w));
            #pragma unroll
            for (int k = 0; k < 6; k++)
                mx = fmaxf(mx, __shfl_xor(mx, 1 << k, 64));
            float e0 = __expf(s.x - mx), e1 = __expf(s.y - mx);
            float e2 = __expf(s.z - mx), e3 = __expf(s.w - mx);
            float ls = e0 + e1 + e2 + e3;
            #pragma unroll
            for (int k = 0; k < 6; k++)
                ls += __shfl_xor(ls, 1 << k, 64);
            float R = 1.f / ls;
            f32x4 p = { e0 * R, e1 * R, e2 * R, e3 * R };
            // full-row wave store: 64 lanes x 16B = contiguous 1KB
            __builtin_nontemporal_store(p, (f32x4*)(arow + ((size_t)m << 8) + 4 * l));
            *(f32x4*)(Pst + r * 260 + 4 * l) = p;
        }
        // ---- Phase B: PV for the 4 staged rows (wave-private, no barrier) ----
        {
            const int d = l >> 2, r = l & 3;
            const int m = mbase + c4 * 4 + r;
            const float* Pr = Pst + r * 260;
            const float* Vr = Vs + d * 260;
            float acc = 0.f;
            #pragma unroll 8
            for (int n4 = 0; n4 < 256; n4 += 4) {
                float4 pv = *(const float4*)(Pr + n4);
                float4 vv = *(const float4*)(Vr + n4);
                acc += pv.x * vv.x + pv.y * vv.y + pv.z * vv.z + pv.w * vv.w;
            }
            out_ws[((size_t)((h * 16 + d) * 256 + wi) << 8) + m] = acc;
        }
    }
}

// ---------------------------------------------------------------------------
// Kernel D: un-window out_ws [c][wi][m] -> NCHW image via LDS transpose.
// ---------------------------------------------------------------------------
__global__ __launch_bounds__(256) void k_unwin(
    const float* __restrict__ src, float* __restrict__ dst)
{
    const int c  = blockIdx.x >> 4;
    const int i2 = blockIdx.x & 15;
    __shared__ float lds[16 * 257];
    const int t = threadIdx.x;
    #pragma unroll
    for (int j2 = 0; j2 < 16; j2++)
        lds[j2 * 257 + t] = src[((size_t)(c * 256 + i2 * 16 + j2) << 8) + t];
    __syncthreads();
    #pragma unroll
    for (int i1 = 0; i1 < 16; i1++) {
        dst[(size_t)c * HW + (i1 * 16 + i2) * 256 + t] =
            lds[(t & 15) * 257 + i1 * 16 + (t >> 4)];
    }
}

// ---------------------------------------------------------------------------
extern "C" void kernel_launch(void* const* d_in, const int* in_sizes, int n_in,
                              void* d_out, int out_size, void* d_ws, size_t ws_size,
                              hipStream_t stream)
{
    const float* lms   = (const float*)d_in[0];
    const float* pan   = (const float*)d_in[1];
    const float* g_ms  = (const float*)d_in[2];
    const float* g_pan = (const float*)d_in[3];
    const float* qw1   = (const float*)d_in[4];
    const float* qb1   = (const float*)d_in[5];
    const float* qw2   = (const float*)d_in[6];
    const float* qb2   = (const float*)d_in[7];
    const float* kvw1  = (const float*)d_in[8];
    const float* kvb1  = (const float*)d_in[9];
    const float* kvw2  = (const float*)d_in[10];
    const float* kvb2  = (const float*)d_in[11];

    float* attn   = (float*)d_out;                       // 256*8*256*256 fp32
    float* outimg = attn + (size_t)134217728;            // 128*256*256 fp32

    char* ws = (char*)d_ws;
    float* q_win  = (float*)(ws);                        //  32 MB [c][wi][m]
    float* kv_win = (float*)(ws + (size_t)33554432);     //  64 MB [c][wi][m]
    float* q_pre  = (float*)(ws + (size_t)100663296);    //  32 MB NCHW
    float* kv_pre = (float*)(ws + (size_t)134217728);    //  64 MB NCHW
    float* out_ws = q_pre;  // overlay: q_pre dead once k_dw3x3(q) is done

    hipLaunchKernelGGL(k_ln_conv1, dim3(256), dim3(256), 0, stream,
                       lms, pan, g_ms, g_pan, qw1, qb1, kvw1, kvb1, q_pre, kv_pre);
    hipLaunchKernelGGL(k_dw3x3, dim3(128 * 16), dim3(256), 0, stream,
                       q_pre, qw2, qb2, q_win);
    hipLaunchKernelGGL(k_dw3x3, dim3(256 * 16), dim3(256), 0, stream,
                       kv_pre, kvw2, kvb2, kv_win);
    hipLaunchKernelGGL(k_attn, dim3(2048), dim3(256), 0, stream,
                       q_win, kv_win, attn, out_ws);
    hipLaunchKernelGGL(k_unwin, dim3(2048), dim3(256), 0, stream,
                       out_ws, outimg);
}